// Round 7
// baseline (234.844 us; speedup 1.0000x reference)
//
#include <hip/hip_runtime.h>

#define DIM 128
#define UNROLL 16
#define BLOCK 256
#define CHUNK (BLOCK * UNROLL)   // float4 units per block = 4096

typedef float nfloat4 __attribute__((ext_vector_type(4)));  // native vector:
// __builtin_nontemporal_* requires a clang vector type, not HIP_vector_type.

// One-shot grid: each 256-thread block handles one contiguous 64 KB chunk of
// the output (4096 float4). Each thread: 16 dist loads -> 16 emb gathers ->
// 16 nt stores, straight-line, so the compiler can keep ~16 stores plus the
// gathers in flight per wave (fillBuffer evidence: 6.5 TB/s at 11% occupancy,
// store BW wants per-wave MLP, not TLP -> trading occupancy 8->4 waves/SIMD
// for 2x in-flight depth is the right direction).
//
// Stores and dist loads are NONTEMPORAL: the 1 GiB write stream and the 8 MB
// read-once dist stream stay out of L2, keeping the 64 KB emb table resident
// so gathers stay L1/L2-fast on the store-dependent chain.
//
// Within a 32-lane group all lanes share one distance (broadcast load) and
// gather one contiguous 512 B emb row (coalesced). Bins stay in LDS (512 B).
__global__ __launch_bounds__(BLOCK, 4) void DistanceEmbedding_kernel(
    const float* __restrict__ dist,    // [R] distances
    const nfloat4* __restrict__ emb4,  // [DIM*DIM/4] table as float4
    const float* __restrict__ bins,    // [DIM] bin centers (monotone)
    nfloat4* __restrict__ out,         // [R*32] output
    unsigned total4)                   // R*32
{
    __shared__ float s_bins[DIM];
    if (threadIdx.x < DIM) s_bins[threadIdx.x] = bins[threadIdx.x];
    __syncthreads();

    // bins = linspace(0, 32, 128), spacing 32/127. Closed-form nearest bin
    // round(d*127/32) is within +/-1 of true argmin; refine against the real
    // bins with first-min tie-break (matches jnp.argmin). absmax==0 verified.
    const float inv_step = 127.0f / 32.0f;

    const unsigned base = blockIdx.x * (unsigned)CHUNK + threadIdx.x;

    float d[UNROLL];
    #pragma unroll
    for (int k = 0; k < UNROLL; ++k) {
        const unsigned t = base + (unsigned)k * BLOCK;
        d[k] = __builtin_nontemporal_load(&dist[min(t, total4 - 1u) >> 5]);
    }

    nfloat4 v[UNROLL];
    #pragma unroll
    for (int k = 0; k < UNROLL; ++k) {
        const unsigned t = base + (unsigned)k * BLOCK;
        const float dk = d[k];
        const float x = dk * inv_step;
        int i0 = (int)floorf(x + 0.5f);
        i0 = min(max(i0, 0), DIM - 1);
        const int lo = max(i0 - 1, 0);
        const int hi = min(i0 + 1, DIM - 1);
        int best = lo;
        float bd = fabsf(dk - s_bins[lo]);
        #pragma unroll
        for (int i = 0; i < 2; ++i) {
            const int cand = lo + 1 + i;
            if (cand <= hi) {
                const float cd = fabsf(dk - s_bins[cand]);
                if (cd < bd) { bd = cd; best = cand; }  // strict <: first-min
            }
        }
        v[k] = emb4[best * (DIM / 4) + (int)(t & 31u)];
    }

    #pragma unroll
    for (int k = 0; k < UNROLL; ++k) {
        const unsigned t = base + (unsigned)k * BLOCK;
        if (t < total4) __builtin_nontemporal_store(v[k], &out[t]);
    }
}

extern "C" void kernel_launch(void* const* d_in, const int* in_sizes, int n_in,
                              void* d_out, int out_size, void* d_ws, size_t ws_size,
                              hipStream_t stream) {
    const float* dist = (const float*)d_in[0];      // [2,1024,1024] f32
    const nfloat4* emb = (const nfloat4*)d_in[1];   // [128,128] f32
    const float* bins = (const float*)d_in[2];      // [128] f32
    nfloat4* out = (nfloat4*)d_out;                 // [2,1024,1024,128] f32

    const unsigned R = (unsigned)in_sizes[0];       // distance elements
    const unsigned total4 = R * (DIM / 4);          // float4 units in output

    const unsigned grid = (total4 + CHUNK - 1) / CHUNK;   // 16384 for bench shape
    DistanceEmbedding_kernel<<<grid, BLOCK, 0, stream>>>(
        dist, emb, bins, out, total4);
}

// Round 8
// 200.742 us; speedup vs baseline: 1.1699x; 1.1699x over previous
//
#include <hip/hip_runtime.h>

#define DIM 128
#define UNROLL 8
#define HALF (UNROLL / 2)
#define BLOCK 256
#define CHUNK (BLOCK * UNROLL)   // float4 units per block = 2048

typedef float nfloat4 __attribute__((ext_vector_type(4)));  // native vector:
// __builtin_nontemporal_store requires a clang vector type, not HIP_vector_type.

// Proven-best config (R6: 203 us) + split gather/store half-batches.
// One-shot grid: each 256-thread block handles one contiguous 32 KB chunk of
// the output (2048 float4); ~128 blocks/CU lifetime so CU imbalance
// amortizes. 8 waves/SIMD (bounds (256,8)); per-thread depth 8 is plenty:
// hitting 6.5 TB/s needs only ~11 B/cy/CU of store issue, so TLP > depth
// (R7's UNROLL=16 at 4 waves/SIMD regressed to 235 us).
//
// Stores are NONTEMPORAL: keeps the 1 GiB write stream from sweeping each
// XCD's 4 MB L2, so the 64 KB emb table stays L2/L1-resident for the gathers
// on the store-dependent chain (R4->R6: 213->203 us). dist loads stay CACHED:
// they are 32-lane broadcast reads, re-hit in L1 (nt on them was part of
// R7's regression).
//
// Half-batch split: gather 4 -> store 4 -> gather 4 -> store 4. First store
// quad issues while the second gather quad is in flight -> earlier
// time-to-first-store, smoother read/write interleave at the vmem port.
__global__ __launch_bounds__(BLOCK, 8) void DistanceEmbedding_kernel(
    const float* __restrict__ dist,    // [R] distances
    const nfloat4* __restrict__ emb4,  // [DIM*DIM/4] table as float4
    const float* __restrict__ bins,    // [DIM] bin centers (monotone)
    nfloat4* __restrict__ out,         // [R*32] output
    unsigned total4)                   // R*32
{
    __shared__ float s_bins[DIM];
    if (threadIdx.x < DIM) s_bins[threadIdx.x] = bins[threadIdx.x];
    __syncthreads();

    // bins = linspace(0, 32, 128), spacing 32/127. Closed-form nearest bin
    // round(d*127/32) is within +/-1 of true argmin; refine against the real
    // bins with first-min tie-break (matches jnp.argmin). absmax==0 verified.
    const float inv_step = 127.0f / 32.0f;

    const unsigned base = blockIdx.x * (unsigned)CHUNK + threadIdx.x;

    // All dist loads up front (they gate everything; L1-broadcast, cheap).
    float d[UNROLL];
    #pragma unroll
    for (int k = 0; k < UNROLL; ++k) {
        const unsigned t = base + (unsigned)k * BLOCK;
        d[k] = dist[min(t, total4 - 1u) >> 5];
    }

    #pragma unroll
    for (int h = 0; h < 2; ++h) {
        nfloat4 v[HALF];
        #pragma unroll
        for (int j = 0; j < HALF; ++j) {
            const int k = h * HALF + j;
            const unsigned t = base + (unsigned)k * BLOCK;
            const float dk = d[k];
            const float x = dk * inv_step;
            int i0 = (int)floorf(x + 0.5f);
            i0 = min(max(i0, 0), DIM - 1);
            const int lo = max(i0 - 1, 0);
            const int hi = min(i0 + 1, DIM - 1);
            int best = lo;
            float bd = fabsf(dk - s_bins[lo]);
            #pragma unroll
            for (int i = 0; i < 2; ++i) {
                const int cand = lo + 1 + i;
                if (cand <= hi) {
                    const float cd = fabsf(dk - s_bins[cand]);
                    if (cd < bd) { bd = cd; best = cand; }  // strict <: first-min
                }
            }
            v[j] = emb4[best * (DIM / 4) + (int)(t & 31u)];
        }

        #pragma unroll
        for (int j = 0; j < HALF; ++j) {
            const int k = h * HALF + j;
            const unsigned t = base + (unsigned)k * BLOCK;
            if (t < total4) __builtin_nontemporal_store(v[j], &out[t]);
        }
    }
}

extern "C" void kernel_launch(void* const* d_in, const int* in_sizes, int n_in,
                              void* d_out, int out_size, void* d_ws, size_t ws_size,
                              hipStream_t stream) {
    const float* dist = (const float*)d_in[0];      // [2,1024,1024] f32
    const nfloat4* emb = (const nfloat4*)d_in[1];   // [128,128] f32
    const float* bins = (const float*)d_in[2];      // [128] f32
    nfloat4* out = (nfloat4*)d_out;                 // [2,1024,1024,128] f32

    const unsigned R = (unsigned)in_sizes[0];       // distance elements
    const unsigned total4 = R * (DIM / 4);          // float4 units in output

    const unsigned grid = (total4 + CHUNK - 1) / CHUNK;   // 32768 for bench shape
    DistanceEmbedding_kernel<<<grid, BLOCK, 0, stream>>>(
        dist, emb, bins, out, total4);
}

// Round 9
// 184.194 us; speedup vs baseline: 1.2750x; 1.0898x over previous
//
#include <hip/hip_runtime.h>

#define DIM 128
#define UNROLL 8
#define BLOCK 1024
#define CHUNK (BLOCK * UNROLL)   // float4 units per block = 8192

typedef float nfloat4 __attribute__((ext_vector_type(4)));  // native vector:
// __builtin_nontemporal_store requires a clang vector type, not HIP_vector_type.

// LDS-gather + fine granularity (the untested quadrant).
// 8192 one-shot blocks of 1024 threads (~32 blocks/CU lifetime -> balanced),
// 2 blocks/CU co-resident (64.5 KB LDS each), 8 waves/SIMD.
//
// emb table staged in LDS once per block: the store-dependent gather moves to
// the lgkm path (ds_read_b128, ~85 B/cy/CU >> the 10.6 B/cy needed), so the
// vmem queue carries ONLY broadcast dist loads + nt stores -- structurally a
// fillBuffer plus a cheap load. Tests whether the residual 14% vs the fill
// ceiling was vmem-port/L1 contention from the gather stream.
//
// Stores NONTEMPORAL (R4->R6 win): 1 GiB write stream bypasses L2 so the
// table + dist lines stay cache-resident.
__global__ __launch_bounds__(BLOCK, 8) void DistanceEmbedding_kernel(
    const float* __restrict__ dist,    // [R] distances
    const nfloat4* __restrict__ emb4,  // [DIM*DIM/4] table as float4
    const float* __restrict__ bins,    // [DIM] bin centers (monotone)
    nfloat4* __restrict__ out,         // [R*32] output
    unsigned total4)                   // R*32
{
    __shared__ float s_bins[DIM];
    __shared__ nfloat4 s_emb[DIM * DIM / 4];   // 64 KB

    #pragma unroll
    for (int i = 0; i < 4; ++i)
        s_emb[threadIdx.x + i * BLOCK] = emb4[threadIdx.x + i * BLOCK];
    if (threadIdx.x < DIM) s_bins[threadIdx.x] = bins[threadIdx.x];
    __syncthreads();

    // bins = linspace(0, 32, 128), spacing 32/127. Closed-form nearest bin
    // round(d*127/32) is within +/-1 of true argmin; refine against the real
    // bins with first-min tie-break (matches jnp.argmin). absmax==0 verified.
    const float inv_step = 127.0f / 32.0f;

    const unsigned base = blockIdx.x * (unsigned)CHUNK + threadIdx.x;

    // All dist loads up front (broadcast within 32-lane groups, L1-hot).
    float d[UNROLL];
    #pragma unroll
    for (int k = 0; k < UNROLL; ++k) {
        const unsigned t = base + (unsigned)k * BLOCK;
        d[k] = dist[min(t, total4 - 1u) >> 5];
    }

    nfloat4 v[UNROLL];
    #pragma unroll
    for (int k = 0; k < UNROLL; ++k) {
        const unsigned t = base + (unsigned)k * BLOCK;
        const float dk = d[k];
        const float x = dk * inv_step;
        int i0 = (int)floorf(x + 0.5f);
        i0 = min(max(i0, 0), DIM - 1);
        const int lo = max(i0 - 1, 0);
        const int hi = min(i0 + 1, DIM - 1);
        int best = lo;
        float bd = fabsf(dk - s_bins[lo]);
        #pragma unroll
        for (int i = 0; i < 2; ++i) {
            const int cand = lo + 1 + i;
            if (cand <= hi) {
                const float cd = fabsf(dk - s_bins[cand]);
                if (cd < bd) { bd = cd; best = cand; }  // strict <: first-min
            }
        }
        v[k] = s_emb[best * (DIM / 4) + (int)(t & 31u)];
    }

    #pragma unroll
    for (int k = 0; k < UNROLL; ++k) {
        const unsigned t = base + (unsigned)k * BLOCK;
        if (t < total4) __builtin_nontemporal_store(v[k], &out[t]);
    }
}

extern "C" void kernel_launch(void* const* d_in, const int* in_sizes, int n_in,
                              void* d_out, int out_size, void* d_ws, size_t ws_size,
                              hipStream_t stream) {
    const float* dist = (const float*)d_in[0];      // [2,1024,1024] f32
    const nfloat4* emb = (const nfloat4*)d_in[1];   // [128,128] f32
    const float* bins = (const float*)d_in[2];      // [128] f32
    nfloat4* out = (nfloat4*)d_out;                 // [2,1024,1024,128] f32

    const unsigned R = (unsigned)in_sizes[0];       // distance elements
    const unsigned total4 = R * (DIM / 4);          // float4 units in output

    const unsigned grid = (total4 + CHUNK - 1) / CHUNK;   // 8192 for bench shape
    DistanceEmbedding_kernel<<<grid, BLOCK, 0, stream>>>(
        dist, emb, bins, out, total4);
}